// Round 3
// baseline (145.802 us; speedup 1.0000x reference)
//
#include <hip/hip_runtime.h>

// Masked scatter-add: out[index[i]] += rate[i] where starttime[i] <= t < endtime[i].
//
// R1: direct global atomics -> 250-way contention at coherence point, 113 us.
// R2: LDS histograms + 2000 partials + atomic reduce, 45 us. Counters: memory-
//     bound (VALUBusy 3.6%), 176 MB effective traffic at ~4.5 TB/s; partials
//     cost 32 MB round trip; rate/index fetched even for inactive chunks.
// R3: npart=512 (8 MB partial RT), conditional rate/index loads (~18.5% of
//     chunks have an active event at 5% activity), reduce does plain stores
//     over a unique bin range -> no memset, no atomics, 2 dispatches.

#define MAX_BINS 2048   // problem SIZE = 2000; static LDS must be compile-time

__global__ void __launch_bounds__(256)
hist_partial_kernel(const int* __restrict__ index,
                    const float* __restrict__ rate,
                    const float* __restrict__ starttime,
                    const float* __restrict__ endtime,
                    const float* __restrict__ t_ptr,
                    float* __restrict__ ws,   // [gridDim.x][size] partials
                    int n, int size)
{
    __shared__ float hist[MAX_BINS];
    for (int j = threadIdx.x; j < size; j += blockDim.x) hist[j] = 0.0f;
    __syncthreads();

    const float t = t_ptr[0];
    const int tid      = blockIdx.x * blockDim.x + threadIdx.x;
    const int nthreads = gridDim.x * blockDim.x;
    const int nvec     = n >> 2;

    const int4*   idx4v = reinterpret_cast<const int4*>(index);
    const float4* rat4v = reinterpret_cast<const float4*>(rate);
    const float4* st4v  = reinterpret_cast<const float4*>(starttime);
    const float4* en4v  = reinterpret_cast<const float4*>(endtime);

    for (int i = tid; i < nvec; i += nthreads) {
        const float4 s4 = st4v[i];
        const float4 e4 = en4v[i];

        const bool a0 = (s4.x <= t) & (t < e4.x);
        const bool a1 = (s4.y <= t) & (t < e4.y);
        const bool a2 = (s4.z <= t) & (t < e4.z);
        const bool a3 = (s4.w <= t) & (t < e4.w);

        // Only ~18.5% of 4-elem chunks contain an active event: skip the
        // rate/index fetch for the rest (cuts HBM lines for those arrays).
        if (a0 | a1 | a2 | a3) {
            const int4   i4 = idx4v[i];
            const float4 r4 = rat4v[i];
            if (a0) atomicAdd(&hist[i4.x], r4.x);   // ds_add_f32, uncontended
            if (a1) atomicAdd(&hist[i4.y], r4.y);
            if (a2) atomicAdd(&hist[i4.z], r4.z);
            if (a3) atomicAdd(&hist[i4.w], r4.w);
        }
    }
    // Tail (N % 4) — N=10M divisible by 4, but stay generic.
    for (int i = (nvec << 2) + tid; i < n; i += nthreads) {
        if (starttime[i] <= t && t < endtime[i]) atomicAdd(&hist[index[i]], rate[i]);
    }

    __syncthreads();

    // Coalesced flush of this block's private partial row (vectorized).
    float* part = ws + (size_t)blockIdx.x * size;
    const int nq = size >> 2;
    float4* part4 = reinterpret_cast<float4*>(part);
    const float4* hist4 = reinterpret_cast<const float4*>(hist);
    for (int j = threadIdx.x; j < nq; j += blockDim.x) part4[j] = hist4[j];
    for (int j = (nq << 2) + threadIdx.x; j < size; j += blockDim.x) part[j] = hist[j];
}

// out[j] = sum_b ws[b][j]. Each j owned by exactly one thread -> plain store,
// covers every bin (no memset needed). Lanes read consecutive j at fixed b ->
// coalesced.
__global__ void __launch_bounds__(256)
reduce_partials_kernel(const float* __restrict__ ws,
                       float* __restrict__ out,
                       int npart, int size)
{
    const int j = blockIdx.x * blockDim.x + threadIdx.x;
    if (j >= size) return;

    float sum = 0.0f;
    int b = 0;
    #pragma unroll 8
    for (; b + 8 <= npart; b += 8) {
        sum += ws[(size_t)(b + 0) * size + j];
        sum += ws[(size_t)(b + 1) * size + j];
        sum += ws[(size_t)(b + 2) * size + j];
        sum += ws[(size_t)(b + 3) * size + j];
        sum += ws[(size_t)(b + 4) * size + j];
        sum += ws[(size_t)(b + 5) * size + j];
        sum += ws[(size_t)(b + 6) * size + j];
        sum += ws[(size_t)(b + 7) * size + j];
    }
    for (; b < npart; ++b) sum += ws[(size_t)b * size + j];

    out[j] = sum;
}

// Fallback (ws too small / size too large): direct predicated global atomics.
__global__ void __launch_bounds__(256)
direct_atomic_kernel(const int* __restrict__ index,
                     const float* __restrict__ rate,
                     const float* __restrict__ starttime,
                     const float* __restrict__ endtime,
                     const float* __restrict__ t_ptr,
                     float* __restrict__ out, int n)
{
    const float t = t_ptr[0];
    const int tid      = blockIdx.x * blockDim.x + threadIdx.x;
    const int nthreads = gridDim.x * blockDim.x;
    for (int i = tid; i < n; i += nthreads) {
        if (starttime[i] <= t && t < endtime[i]) atomicAdd(&out[index[i]], rate[i]);
    }
}

extern "C" void kernel_launch(void* const* d_in, const int* in_sizes, int n_in,
                              void* d_out, int out_size, void* d_ws, size_t ws_size,
                              hipStream_t stream)
{
    const int*   index     = (const int*)  d_in[0];
    const float* rate      = (const float*)d_in[1];
    const float* starttime = (const float*)d_in[2];
    const float* endtime   = (const float*)d_in[3];
    const float* t_ptr     = (const float*)d_in[4];

    float* out = (float*)d_out;
    float* ws  = (float*)d_ws;
    const int n    = in_sizes[0];
    const int size = out_size;

    const int block = 256;

    // Partial-histogram count bounded by workspace; 512 is the sweet spot:
    // 2 blocks/CU (8 waves/CU, ample for latency hiding) and only 4 MB of
    // partial traffic each way.
    int npart = (int)(ws_size / ((size_t)size * sizeof(float)));
    if (npart > 512) npart = 512;

    if (size <= MAX_BINS && npart >= 64) {
        hist_partial_kernel<<<npart, block, 0, stream>>>(
            index, rate, starttime, endtime, t_ptr, ws, n, size);

        reduce_partials_kernel<<<(size + block - 1) / block, block, 0, stream>>>(
            ws, out, npart, size);
    } else {
        hipMemsetAsync(out, 0, (size_t)size * sizeof(float), stream);
        int grid = (n + block - 1) / block;
        if (grid > 2048) grid = 2048;
        direct_atomic_kernel<<<grid, block, 0, stream>>>(
            index, rate, starttime, endtime, t_ptr, out, n);
    }
}

// Round 4
// 36.491 us; speedup vs baseline: 3.9955x; 3.9955x over previous
//
#include <hip/hip_runtime.h>

// Masked scatter-add: out[index[i]] += rate[i] where starttime[i] <= t < endtime[i].
//
// R1: direct global atomics -> 250-way contention at memory side, 113 us.
// R2: LDS hist + 2000 partials + atomic reduce (y=8): 45 us.
// R3: npart=512 + conditional idx/rate loads made hist ~26 us, BUT the
//     plain-store reduce (one thread per bin = 8 workgroups total) was
//     latency-bound at 118 us (0.34% occupancy, ~550 cyc per load, 18 GB/s).
// R4: keep R3's hist (plus 2-point grid-stride for more loads in flight);
//     reduce goes back to parallel-over-partials: 128 blocks, 32 loads/thread,
//     one atomicAdd per thread (16-way/bin contention -- negligible). Memset out.

#define MAX_BINS 2048   // problem SIZE = 2000; static LDS must be compile-time

__global__ void __launch_bounds__(256)
hist_partial_kernel(const int* __restrict__ index,
                    const float* __restrict__ rate,
                    const float* __restrict__ starttime,
                    const float* __restrict__ endtime,
                    const float* __restrict__ t_ptr,
                    float* __restrict__ ws,   // [gridDim.x][size] partials
                    int n, int size)
{
    __shared__ float hist[MAX_BINS];
    for (int j = threadIdx.x; j < size; j += blockDim.x) hist[j] = 0.0f;
    __syncthreads();

    const float t = t_ptr[0];
    const int tid      = blockIdx.x * blockDim.x + threadIdx.x;
    const int nthreads = gridDim.x * blockDim.x;
    const int nvec     = n >> 2;

    const int4*   idx4v = reinterpret_cast<const int4*>(index);
    const float4* rat4v = reinterpret_cast<const float4*>(rate);
    const float4* st4v  = reinterpret_cast<const float4*>(starttime);
    const float4* en4v  = reinterpret_cast<const float4*>(endtime);

    // Latency-bound (R2/R3 counters: HBM <20% peak, VALUBusy <4%): process two
    // independent grid-stride points per iteration so 4 coalesced s/e float4
    // loads are in flight per thread.
    for (int i = tid; i < nvec; i += 2 * nthreads) {
        const int  ib   = i + nthreads;
        const bool hasB = (ib < nvec);

        const float4 sA = st4v[i];
        const float4 eA = en4v[i];
        float4 sB, eB;
        if (hasB) { sB = st4v[ib]; eB = en4v[ib]; }

        const bool a0 = (sA.x <= t) & (t < eA.x);
        const bool a1 = (sA.y <= t) & (t < eA.y);
        const bool a2 = (sA.z <= t) & (t < eA.z);
        const bool a3 = (sA.w <= t) & (t < eA.w);
        // ~18.5% of chunks contain an active event: skip idx/rate fetch otherwise.
        if (a0 | a1 | a2 | a3) {
            const int4   i4 = idx4v[i];
            const float4 r4 = rat4v[i];
            if (a0) atomicAdd(&hist[i4.x], r4.x);   // ds_add_f32, uncontended
            if (a1) atomicAdd(&hist[i4.y], r4.y);
            if (a2) atomicAdd(&hist[i4.z], r4.z);
            if (a3) atomicAdd(&hist[i4.w], r4.w);
        }

        if (hasB) {
            const bool b0 = (sB.x <= t) & (t < eB.x);
            const bool b1 = (sB.y <= t) & (t < eB.y);
            const bool b2 = (sB.z <= t) & (t < eB.z);
            const bool b3 = (sB.w <= t) & (t < eB.w);
            if (b0 | b1 | b2 | b3) {
                const int4   i4 = idx4v[ib];
                const float4 r4 = rat4v[ib];
                if (b0) atomicAdd(&hist[i4.x], r4.x);
                if (b1) atomicAdd(&hist[i4.y], r4.y);
                if (b2) atomicAdd(&hist[i4.z], r4.z);
                if (b3) atomicAdd(&hist[i4.w], r4.w);
            }
        }
    }
    // Tail (N % 4) — N=10M divisible by 4, but stay generic.
    for (int i = (nvec << 2) + tid; i < n; i += nthreads) {
        if (starttime[i] <= t && t < endtime[i]) atomicAdd(&hist[index[i]], rate[i]);
    }

    __syncthreads();

    // Coalesced, vectorized flush of this block's private partial row.
    float* part = ws + (size_t)blockIdx.x * size;
    const int nq = size >> 2;
    float4* part4 = reinterpret_cast<float4*>(part);
    const float4* hist4 = reinterpret_cast<const float4*>(hist);
    for (int j = threadIdx.x; j < nq; j += blockDim.x) part4[j] = hist4[j];
    for (int j = (nq << 2) + threadIdx.x; j < size; j += blockDim.x) part[j] = hist[j];
}

// Parallel over partials: block (x=j-tile, y=b-chunk). Each thread sums its
// chunk (coalesced: lanes read consecutive j at fixed b) then ONE atomicAdd.
// gridDim.y-way contention per bin -- negligible.
__global__ void __launch_bounds__(256)
reduce_partials_kernel(const float* __restrict__ ws,
                       float* __restrict__ out,
                       int npart, int size)
{
    const int j = blockIdx.x * blockDim.x + threadIdx.x;
    if (j >= size) return;

    const int chunk  = npart / gridDim.y;
    const int bstart = blockIdx.y * chunk;
    const int bend   = (blockIdx.y == gridDim.y - 1) ? npart : bstart + chunk;

    float sum = 0.0f;
    int b = bstart;
    #pragma unroll 8
    for (; b + 8 <= bend; b += 8) {
        sum += ws[(size_t)(b + 0) * size + j];
        sum += ws[(size_t)(b + 1) * size + j];
        sum += ws[(size_t)(b + 2) * size + j];
        sum += ws[(size_t)(b + 3) * size + j];
        sum += ws[(size_t)(b + 4) * size + j];
        sum += ws[(size_t)(b + 5) * size + j];
        sum += ws[(size_t)(b + 6) * size + j];
        sum += ws[(size_t)(b + 7) * size + j];
    }
    for (; b < bend; ++b) sum += ws[(size_t)b * size + j];

    atomicAdd(&out[j], sum);
}

// Fallback (ws too small / size too large): direct predicated global atomics.
__global__ void __launch_bounds__(256)
direct_atomic_kernel(const int* __restrict__ index,
                     const float* __restrict__ rate,
                     const float* __restrict__ starttime,
                     const float* __restrict__ endtime,
                     const float* __restrict__ t_ptr,
                     float* __restrict__ out, int n)
{
    const float t = t_ptr[0];
    const int tid      = blockIdx.x * blockDim.x + threadIdx.x;
    const int nthreads = gridDim.x * blockDim.x;
    for (int i = tid; i < n; i += nthreads) {
        if (starttime[i] <= t && t < endtime[i]) atomicAdd(&out[index[i]], rate[i]);
    }
}

extern "C" void kernel_launch(void* const* d_in, const int* in_sizes, int n_in,
                              void* d_out, int out_size, void* d_ws, size_t ws_size,
                              hipStream_t stream)
{
    const int*   index     = (const int*)  d_in[0];
    const float* rate      = (const float*)d_in[1];
    const float* starttime = (const float*)d_in[2];
    const float* endtime   = (const float*)d_in[3];
    const float* t_ptr     = (const float*)d_in[4];

    float* out = (float*)d_out;
    float* ws  = (float*)d_ws;
    const int n    = in_sizes[0];
    const int size = out_size;

    const int block = 256;

    // Atomic reduce accumulates into d_out -> zero it every call (replays are
    // not re-poisoned by the harness).
    hipMemsetAsync(out, 0, (size_t)size * sizeof(float), stream);

    // npart=512: 2 blocks/CU for the hist (8 waves/CU), 4 MB partial traffic.
    int npart = (int)(ws_size / ((size_t)size * sizeof(float)));
    if (npart > 512) npart = 512;

    if (size <= MAX_BINS && npart >= 64) {
        hist_partial_kernel<<<npart, block, 0, stream>>>(
            index, rate, starttime, endtime, t_ptr, ws, n, size);

        dim3 g2((size + block - 1) / block, 16);   // 128 blocks, 32 loads/thread
        reduce_partials_kernel<<<g2, block, 0, stream>>>(ws, out, npart, size);
    } else {
        int grid = (n + block - 1) / block;
        if (grid > 2048) grid = 2048;
        direct_atomic_kernel<<<grid, block, 0, stream>>>(
            index, rate, starttime, endtime, t_ptr, out, n);
    }
}

// Round 5
// 35.429 us; speedup vs baseline: 4.1153x; 1.0300x over previous
//
#include <hip/hip_runtime.h>

// Masked scatter-add: out[index[i]] += rate[i] where starttime[i] <= t < endtime[i].
//
// R1: direct global atomics -> 250-way memory-side contention, 113 us.
// R2: LDS hist + 2000 partials + atomic reduce: 45 us.
// R3: plain-store reduce (8 workgroups) was latency-bound at 118 us. Hist with
//     conditional idx/rate loads ~26 us.
// R4: parallel reduce restored -> 36.5 us total. Hist counters: Occupancy 18%
//     (npart=512 x 256thr = 8 waves/CU), HBM 1.5 TB/s, VALUBusy 2.6% ->
//     still latency-bound, capped by our own grid.
// R5: same grid (512 blocks -> partials stay 4 MB) but 1024 threads/block:
//     16 waves x 2 blocks/CU = 32 waves/CU = 100% occupancy, 4x the loads
//     in flight. Reduce unchanged.

#define MAX_BINS 2048   // problem SIZE = 2000; static LDS must be compile-time
#define HIST_BLOCK 1024

__global__ void __launch_bounds__(HIST_BLOCK)
hist_partial_kernel(const int* __restrict__ index,
                    const float* __restrict__ rate,
                    const float* __restrict__ starttime,
                    const float* __restrict__ endtime,
                    const float* __restrict__ t_ptr,
                    float* __restrict__ ws,   // [gridDim.x][size] partials
                    int n, int size)
{
    __shared__ float hist[MAX_BINS];
    for (int j = threadIdx.x; j < size; j += blockDim.x) hist[j] = 0.0f;
    __syncthreads();

    const float t = t_ptr[0];
    const int tid      = blockIdx.x * blockDim.x + threadIdx.x;
    const int nthreads = gridDim.x * blockDim.x;
    const int nvec     = n >> 2;

    const int4*   idx4v = reinterpret_cast<const int4*>(index);
    const float4* rat4v = reinterpret_cast<const float4*>(rate);
    const float4* st4v  = reinterpret_cast<const float4*>(starttime);
    const float4* en4v  = reinterpret_cast<const float4*>(endtime);

    // Two independent grid-stride points per iteration (ILP) on top of
    // 32 waves/CU (TLP): plenty of coalesced loads in flight.
    for (int i = tid; i < nvec; i += 2 * nthreads) {
        const int  ib   = i + nthreads;
        const bool hasB = (ib < nvec);

        const float4 sA = st4v[i];
        const float4 eA = en4v[i];
        float4 sB, eB;
        if (hasB) { sB = st4v[ib]; eB = en4v[ib]; }

        const bool a0 = (sA.x <= t) & (t < eA.x);
        const bool a1 = (sA.y <= t) & (t < eA.y);
        const bool a2 = (sA.z <= t) & (t < eA.z);
        const bool a3 = (sA.w <= t) & (t < eA.w);
        // ~18.5% of chunks contain an active event: skip idx/rate fetch otherwise.
        if (a0 | a1 | a2 | a3) {
            const int4   i4 = idx4v[i];
            const float4 r4 = rat4v[i];
            if (a0) atomicAdd(&hist[i4.x], r4.x);   // ds_add_f32, uncontended
            if (a1) atomicAdd(&hist[i4.y], r4.y);
            if (a2) atomicAdd(&hist[i4.z], r4.z);
            if (a3) atomicAdd(&hist[i4.w], r4.w);
        }

        if (hasB) {
            const bool b0 = (sB.x <= t) & (t < eB.x);
            const bool b1 = (sB.y <= t) & (t < eB.y);
            const bool b2 = (sB.z <= t) & (t < eB.z);
            const bool b3 = (sB.w <= t) & (t < eB.w);
            if (b0 | b1 | b2 | b3) {
                const int4   i4 = idx4v[ib];
                const float4 r4 = rat4v[ib];
                if (b0) atomicAdd(&hist[i4.x], r4.x);
                if (b1) atomicAdd(&hist[i4.y], r4.y);
                if (b2) atomicAdd(&hist[i4.z], r4.z);
                if (b3) atomicAdd(&hist[i4.w], r4.w);
            }
        }
    }
    // Tail (N % 4) — N=10M divisible by 4, but stay generic.
    for (int i = (nvec << 2) + tid; i < n; i += nthreads) {
        if (starttime[i] <= t && t < endtime[i]) atomicAdd(&hist[index[i]], rate[i]);
    }

    __syncthreads();

    // Coalesced, vectorized flush of this block's private partial row.
    float* part = ws + (size_t)blockIdx.x * size;
    const int nq = size >> 2;
    float4* part4 = reinterpret_cast<float4*>(part);
    const float4* hist4 = reinterpret_cast<const float4*>(hist);
    for (int j = threadIdx.x; j < nq; j += blockDim.x) part4[j] = hist4[j];
    for (int j = (nq << 2) + threadIdx.x; j < size; j += blockDim.x) part[j] = hist[j];
}

// Parallel over partials: block (x=j-tile, y=b-chunk). Each thread sums its
// chunk (coalesced: lanes read consecutive j at fixed b) then ONE atomicAdd.
// gridDim.y-way contention per bin -- negligible.
__global__ void __launch_bounds__(256)
reduce_partials_kernel(const float* __restrict__ ws,
                       float* __restrict__ out,
                       int npart, int size)
{
    const int j = blockIdx.x * blockDim.x + threadIdx.x;
    if (j >= size) return;

    const int chunk  = npart / gridDim.y;
    const int bstart = blockIdx.y * chunk;
    const int bend   = (blockIdx.y == gridDim.y - 1) ? npart : bstart + chunk;

    float sum = 0.0f;
    int b = bstart;
    #pragma unroll 8
    for (; b + 8 <= bend; b += 8) {
        sum += ws[(size_t)(b + 0) * size + j];
        sum += ws[(size_t)(b + 1) * size + j];
        sum += ws[(size_t)(b + 2) * size + j];
        sum += ws[(size_t)(b + 3) * size + j];
        sum += ws[(size_t)(b + 4) * size + j];
        sum += ws[(size_t)(b + 5) * size + j];
        sum += ws[(size_t)(b + 6) * size + j];
        sum += ws[(size_t)(b + 7) * size + j];
    }
    for (; b < bend; ++b) sum += ws[(size_t)b * size + j];

    atomicAdd(&out[j], sum);
}

// Fallback (ws too small / size too large): direct predicated global atomics.
__global__ void __launch_bounds__(256)
direct_atomic_kernel(const int* __restrict__ index,
                     const float* __restrict__ rate,
                     const float* __restrict__ starttime,
                     const float* __restrict__ endtime,
                     const float* __restrict__ t_ptr,
                     float* __restrict__ out, int n)
{
    const float t = t_ptr[0];
    const int tid      = blockIdx.x * blockDim.x + threadIdx.x;
    const int nthreads = gridDim.x * blockDim.x;
    for (int i = tid; i < n; i += nthreads) {
        if (starttime[i] <= t && t < endtime[i]) atomicAdd(&out[index[i]], rate[i]);
    }
}

extern "C" void kernel_launch(void* const* d_in, const int* in_sizes, int n_in,
                              void* d_out, int out_size, void* d_ws, size_t ws_size,
                              hipStream_t stream)
{
    const int*   index     = (const int*)  d_in[0];
    const float* rate      = (const float*)d_in[1];
    const float* starttime = (const float*)d_in[2];
    const float* endtime   = (const float*)d_in[3];
    const float* t_ptr     = (const float*)d_in[4];

    float* out = (float*)d_out;
    float* ws  = (float*)d_ws;
    const int n    = in_sizes[0];
    const int size = out_size;

    // Atomic reduce accumulates into d_out -> zero it every call (replays are
    // not re-poisoned by the harness).
    hipMemsetAsync(out, 0, (size_t)size * sizeof(float), stream);

    // npart=512 partial rows (4 MB traffic), but 1024 threads/block:
    // 16 waves x 2 blocks/CU = 32 waves/CU = 100% occupancy.
    int npart = (int)(ws_size / ((size_t)size * sizeof(float)));
    if (npart > 512) npart = 512;

    if (size <= MAX_BINS && npart >= 64) {
        hist_partial_kernel<<<npart, HIST_BLOCK, 0, stream>>>(
            index, rate, starttime, endtime, t_ptr, ws, n, size);

        dim3 g2((size + 255) / 256, 16);   // 128 blocks, 32 loads/thread
        reduce_partials_kernel<<<g2, 256, 0, stream>>>(ws, out, npart, size);
    } else {
        int grid = (n + 255) / 256;
        if (grid > 2048) grid = 2048;
        direct_atomic_kernel<<<grid, 256, 0, stream>>>(
            index, rate, starttime, endtime, t_ptr, out, n);
    }
}